// Round 2
// baseline (293.357 us; speedup 1.0000x reference)
//
#include <hip/hip_runtime.h>
#include <stdint.h>
#include <math.h>

// Problem constants (fixed by the reference)
constexpr int CB = 2;      // batch
constexpr int CS = 2048;   // seq (cutoff)
constexpr int CD = 1024;   // dmodel
constexpr int CE = 16;     // experts
constexpr int CK = 256;    // topk

typedef short bf16x8 __attribute__((ext_vector_type(8)));
typedef float f32x4 __attribute__((ext_vector_type(4)));

typedef __attribute__((address_space(1))) const unsigned int gu32;
typedef __attribute__((address_space(3))) unsigned int lu32;
typedef __attribute__((address_space(3))) unsigned short lds_us;

__device__ __forceinline__ void async16(const void* g, lds_us* l) {
    __builtin_amdgcn_global_load_lds((gu32*)g, (lu32*)l, 16, 0, 0);
}

// ds_read_b128 hidden from the waitcnt legalizer (it would otherwise insert
// s_waitcnt vmcnt(0) before any visible LDS read aliasing the LDS-DMA).
__device__ __forceinline__ bf16x8 ds_read128(const lds_us* p) {
    bf16x8 v;
    asm volatile("ds_read_b128 %0, %1" : "=v"(v) : "v"(p));
    return v;
}

__device__ inline unsigned short f2bf(float f) {
    union { float f; uint32_t u; } v; v.f = f;
    uint32_t u = v.u;
    uint32_t r = (u + 0x7FFFu + ((u >> 16) & 1u)) >> 16;
    return (unsigned short)r;
}

// ---------------- K1a: partial logits over a 64-d slice (+ zero y) ----------
__global__ __launch_bounds__(256)
void logits_part_kernel(const float* __restrict__ x,
                        const float* __restrict__ gate,
                        float* __restrict__ part,
                        float* __restrict__ y) {
    const int tt = blockIdx.x;       // token tile (256 tokens)
    const int dt = blockIdx.y;       // d tile (64 d)
    const int tid = threadIdx.x;

    // fold the y-zeroing in here (saves a hipMemsetAsync launch node).
    // 256 blocks x 16384 floats each = CB*CS*CD.
    {
        const int bb = dt * 16 + tt;
        float* yb = y + (size_t)bb * 16384 + tid * 4;
        const f32x4 z = {0.f, 0.f, 0.f, 0.f};
#pragma unroll
        for (int i = 0; i < 16; i++) *(f32x4*)(yb + i * 1024) = z;
    }

    __shared__ float Xs[256 * 17];

    float acc[CE];
#pragma unroll
    for (int e = 0; e < CE; e++) acc[e] = 0.0f;

    const int tokl = tid >> 2;           // staging row within 64-token group
    const int c4 = (tid & 3) << 2;       // staging col (0,4,8,12)

    for (int dch = 0; dch < 4; dch++) {
        const int dbase = dt * 64 + dch * 16;
        __syncthreads();
#pragma unroll
        for (int q = 0; q < 4; q++) {
            const int tok = q * 64 + tokl;
            const f32x4 v = *(const f32x4*)(x + ((size_t)(tt * 256 + tok)) * CD + dbase + c4);
            Xs[tok * 17 + c4 + 0] = v[0];
            Xs[tok * 17 + c4 + 1] = v[1];
            Xs[tok * 17 + c4 + 2] = v[2];
            Xs[tok * 17 + c4 + 3] = v[3];
        }
        __syncthreads();
#pragma unroll
        for (int d = 0; d < 16; d++) {
            const float xv = Xs[tid * 17 + d];
            const float* gr = gate + (size_t)(dbase + d) * CE;  // wave-uniform
#pragma unroll
            for (int e = 0; e < CE; e++) acc[e] = fmaf(xv, gr[e], acc[e]);
        }
    }
    float* pr = part + ((size_t)dt * (CB * CS) + tt * 256 + tid) * CE;
#pragma unroll
    for (int e = 0; e < CE; e++) pr[e] = acc[e];
}

// ---------------- K2: per (b,e) softmax over tokens + top-256 ----------------
// Reads the 16 d-partials directly (same deterministic p-order sum as the old
// reduce kernel -> bit-identical logits, one less launch).
__global__ void topk_kernel(const float* __restrict__ part,
                            int* __restrict__ idx_out,
                            float* __restrict__ g_out) {
    const int be = blockIdx.x;            // b*E + e
    const int b = be >> 4, e = be & 15;
    const int tid = threadIdx.x;          // 256
    const int lane = tid & 63, wid = tid >> 6;

    __shared__ float redf[4];
    __shared__ int hist[256];
    __shared__ int wsum[4];
    __shared__ int sh_bin, sh_rank;
    __shared__ int scnt, eqc;
    __shared__ int eqbuf[CS];

    float lv[8], p[8];
    unsigned int uv[8];
#pragma unroll
    for (int j = 0; j < 8; j++) {
        const int s = tid + j * 256;
        const size_t base = ((size_t)(b * CS + s)) * CE + e;
        float sum = 0.0f;
#pragma unroll
        for (int pp = 0; pp < 16; pp++) sum += part[(size_t)pp * (CB * CS * CE) + base];
        lv[j] = sum;
    }
    float m = lv[0];
#pragma unroll
    for (int j = 1; j < 8; j++) m = fmaxf(m, lv[j]);
#pragma unroll
    for (int o = 32; o > 0; o >>= 1) m = fmaxf(m, __shfl_down(m, o));
    if (lane == 0) redf[wid] = m;
    __syncthreads();
    m = fmaxf(fmaxf(redf[0], redf[1]), fmaxf(redf[2], redf[3]));
    __syncthreads();
    float lsum = 0.0f;
#pragma unroll
    for (int j = 0; j < 8; j++) {
        p[j] = expf(lv[j] - m);
        uv[j] = __float_as_uint(p[j]);
        lsum += p[j];
    }
#pragma unroll
    for (int o = 32; o > 0; o >>= 1) lsum += __shfl_down(lsum, o);
    if (lane == 0) redf[wid] = lsum;
    __syncthreads();
    const float total = redf[0] + redf[1] + redf[2] + redf[3];
    const float inv_total = 1.0f / total;

    // ---- radix-256 select: find v = CK-th largest bit pattern ----
    unsigned int prefix = 0;
    int kneed = CK;
    for (int pass = 0; pass < 4; pass++) {
        const int shift = 24 - 8 * pass;
        __syncthreads();
        hist[tid] = 0;
        __syncthreads();
        const unsigned int hmask = (pass == 0) ? 0u : (0xFFFFFFFFu << (shift + 8));
#pragma unroll
        for (int j = 0; j < 8; j++)
            if ((uv[j] & hmask) == prefix)
                atomicAdd(&hist[(uv[j] >> shift) & 255], 1);
        __syncthreads();
        const int own = hist[tid];
        int s = own;
#pragma unroll
        for (int o = 1; o < 64; o <<= 1) {
            int t = __shfl_down(s, o);
            if (lane + o < 64) s += t;
        }
        if (lane == 0) wsum[wid] = s;
        __syncthreads();
        int above = 0;
        for (int ww = wid + 1; ww < 4; ww++) above += wsum[ww];
        const int incl = s + above;
        if (incl >= kneed && (incl - own) < kneed) {
            sh_bin = tid;
            sh_rank = kneed - (incl - own);
        }
        __syncthreads();
        prefix |= ((unsigned int)sh_bin) << shift;
        kneed = sh_rank;
    }
    const unsigned int v = prefix;
    const int quota = kneed;

    if (tid == 0) { scnt = 0; eqc = 0; }
    __syncthreads();
#pragma unroll
    for (int j = 0; j < 8; j++) {
        const int s = tid + j * 256;
        if (uv[j] > v) {
            const int pos = atomicAdd(&scnt, 1);
            idx_out[be * CK + pos] = s;
            g_out[be * CK + pos] = p[j] * inv_total;
        } else if (uv[j] == v) {
            const int pos = atomicAdd(&eqc, 1);
            eqbuf[pos] = s;
        }
    }
    __syncthreads();
    if (tid == 0) {
        const int cgt = scnt;
        const int n = eqc;
        const float gv = __uint_as_float(v) * inv_total;
        if (n > quota) {
            for (int i = 0; i < quota; i++) {
                int mn = i;
                for (int k2 = i + 1; k2 < n; k2++)
                    if (eqbuf[k2] < eqbuf[mn]) mn = k2;
                const int t2 = eqbuf[i]; eqbuf[i] = eqbuf[mn]; eqbuf[mn] = t2;
            }
        }
        for (int i = 0; i < quota; i++) {
            idx_out[be * CK + cgt + i] = eqbuf[i];
            g_out[be * CK + cgt + i] = gv;
        }
    }
}

// ---------------- wt transpose body: W[e][k][n] fp32 -> Wt[e][n][k] bf16 -----
__device__ __forceinline__
void wt_body(const float* __restrict__ W, unsigned short* __restrict__ Wt,
             int kt, int nt, int e, int tid, unsigned short* T) {
    const float* src = W + (size_t)e * CD * CD;
    unsigned short* dst = Wt + (size_t)e * CD * CD;

    const int kr = tid >> 4;            // 0..15
    const int n4 = (tid & 15) << 2;     // 0,4,..,60
#pragma unroll
    for (int it = 0; it < 4; it++) {
        const int k = it * 16 + kr;                    // tile-local k 0..63
        const f32x4 v = *(const f32x4*)(src + (size_t)(kt * 64 + k) * CD + nt * 64 + n4);
        const int pp = k >> 4;                          // 16-short chunk 0..3
        const int klo = k & 15;
#pragma unroll
        for (int i = 0; i < 4; i++) {
            const int n = n4 + i;
            T[n * 64 + ((pp ^ ((n >> 2) & 3)) << 4) + klo] = f2bf(v[i]);
        }
    }
    __syncthreads();
    const int n = tid >> 2;             // 0..63
    const int pp = tid & 3;             // output k-chunk
    const int sw = pp ^ ((n >> 2) & 3);
    const uint4 a = *(const uint4*)&T[n * 64 + (sw << 4)];
    const uint4 b = *(const uint4*)&T[n * 64 + (sw << 4) + 8];
    unsigned short* drow = dst + (size_t)(nt * 64 + n) * CD + kt * 64 + pp * 16;
    *(uint4*)drow = a;
    *(uint4*)(drow + 8) = b;
}

__global__ __launch_bounds__(256)
void wt_kernel(const float* __restrict__ W, unsigned short* __restrict__ Wt) {
    __shared__ unsigned short T[64 * 64];
    wt_body(W, Wt, blockIdx.x, blockIdx.y, blockIdx.z, threadIdx.x, T);
}

// ---------------- prep: wt(W1) and gather fused (one launch) -----------------
__global__ __launch_bounds__(256)
void prep_kernel(const float* __restrict__ W1, unsigned short* __restrict__ Wt,
                 const float* __restrict__ x, const int* __restrict__ idx_ws,
                 unsigned short* __restrict__ xinbuf) {
    __shared__ unsigned short T[64 * 64];
    const int bx = blockIdx.x;
    if (bx < 4096) {
        // wt(W1): kt = bx&15, nt = (bx>>4)&15, e = bx>>8
        wt_body(W1, Wt, bx & 15, (bx >> 4) & 15, bx >> 8, threadIdx.x, T);
    } else {
        // gather selected tokens -> bf16
        const int row = bx - 4096;             // be*CK + slot
        const int be = row >> 8;
        const int b = be >> 4;
        const int tok = idx_ws[row];
        const int c0 = threadIdx.x * 4;
        const f32x4 f = *(const f32x4*)(x + ((size_t)b * CS + tok) * CD + c0);
        union { unsigned short u[4]; uint2 v; } t;
        t.u[0] = f2bf(f[0]); t.u[1] = f2bf(f[1]); t.u[2] = f2bf(f[2]); t.u[3] = f2bf(f[3]);
        *(uint2*)(xinbuf + (size_t)row * CD + c0) = t.v;
    }
}

// ---------------- K5/K6: batched GEMM per (b,e) -- TLP variant ---------------
// Tile 64x128, BK=32, 3-stage LDS ring (36 KB) -> 4 blocks/CU (grid 1024),
// 16 waves/CU. 256 threads = 4 waves, wave-grid 1(M)x4(N), wave tile 64x32,
// acc 4x2. R0's proven counted-vmcnt 2-barrier schedule (3 loads/thread/step,
// steady-state vmcnt(6), drain only in last 2 steps). XOR swizzle c^(row&3)
// on both global source and LDS read (within each 8-lane b128 group this is
// 2-way bank sharing = free per m136).
// Theory: the ~48 us plateau across R0/R1 schedules with all pipes <20% busy
// is latency/serialization of ONE barrier-lockstepped block per CU; 4
// independent blocks/CU hide each other's stalls (m114 mechanism).
#define MFMA16(A_, B_, C_) __builtin_amdgcn_mfma_f32_16x16x32_bf16((A_), (B_), (C_), 0, 0, 0)

template <int PHASE>
__global__ __launch_bounds__(256, 4)
void ffn_gemm(const unsigned short* __restrict__ Ain,
              const unsigned short* __restrict__ Wt,
              const float* __restrict__ bias,
              unsigned short* __restrict__ hout,
              const int* __restrict__ idx_ws,
              const float* __restrict__ g_ws,
              float* __restrict__ y) {
    const int id = blockIdx.x;            // 0..1023, xcd = id&7
    const int xcd = id & 7;
    const int q = id >> 3;                // 0..127
    const int e = ((q & 1) << 3) | xcd;
    const int b = (q >> 1) & 1;
    const int mtile = (q >> 2) & 3;       // 0..3 (64-row slabs of CK=256)
    const int ntile = q >> 4;             // 0..7 (128-col slabs of CD)
    const int be = b * CE + e;
    const int tid = threadIdx.x;
    const int w = tid >> 6, l = tid & 63; // wave = N-column owner (wn = w)
    const int quad = l >> 4, lr = l & 15;

    __shared__ __align__(16) unsigned short As_s[3][64 * 32];    // 3 x 4 KB
    __shared__ __align__(16) unsigned short Bs_s[3][128 * 32];   // 3 x 8 KB

    f32x4 acc[4][2];
    const f32x4 zz = {0.f, 0.f, 0.f, 0.f};
#pragma unroll
    for (int mi = 0; mi < 4; mi++)
#pragma unroll
        for (int ni = 0; ni < 2; ni++) acc[mi][ni] = zz;

    const unsigned short* Abase = Ain + ((size_t)be * CK + mtile * 64) * CD;    // [64][1024]
    const unsigned short* Bbase = Wt + ((size_t)e * CD + ntile * 128) * CD;     // [128][1024]

    // staging units (16B chunks). LDS dest lane-linear; global chunk XOR'd.
    // A: 64 rows x 4 chunks = 256 units -> 1/thread
    const int rA = tid >> 2;
    const int cA = (tid & 3) ^ (rA & 3);
    const size_t gA = (size_t)rA * CD + cA * 8;
    const int dA = tid * 8;
    // B: 128 rows x 4 chunks = 512 units -> 2/thread
    size_t gB[2]; int dB[2];
#pragma unroll
    for (int j = 0; j < 2; j++) {
        const int u = tid + j * 256;
        const int rB = u >> 2;
        const int cB = (u & 3) ^ (rB & 3);
        gB[j] = (size_t)rB * CD + cB * 8;
        dB[j] = u * 8;
    }

    // fragment read offsets: row*32 + ((quad ^ (row&3))*8); row&3 == lr&3
    const int sc = (quad ^ (lr & 3)) * 8;
    int offA[4], offB[2];
#pragma unroll
    for (int mi = 0; mi < 4; mi++) offA[mi] = (mi * 16 + lr) * 32 + sc;
#pragma unroll
    for (int ni = 0; ni < 2; ni++) offB[ni] = (w * 32 + ni * 16 + lr) * 32 + sc;

    lds_us* pa0 = (lds_us*)As_s[0]; lds_us* pa1 = (lds_us*)As_s[1]; lds_us* pa2 = (lds_us*)As_s[2];
    lds_us* pb0 = (lds_us*)Bs_s[0]; lds_us* pb1 = (lds_us*)Bs_s[1]; lds_us* pb2 = (lds_us*)Bs_s[2];

    // prologue: tiles 0,1 -> stages 0,1 (3 loads/thread each)
    async16(Abase + gA, pa0 + dA);
    async16(Bbase + gB[0], pb0 + dB[0]);
    async16(Bbase + gB[1], pb0 + dB[1]);
    async16(Abase + gA + 32, pa1 + dA);
    async16(Bbase + gB[0] + 32, pb1 + dB[0]);
    async16(Bbase + gB[1] + 32, pb1 + dB[1]);

    for (int t = 0; t < 32; t++) {
        if (t < 30) {
            const int k2 = (t + 2) * 32;
            async16(Abase + gA + k2, pa2 + dA);
            async16(Bbase + gB[0] + k2, pb2 + dB[0]);
            async16(Bbase + gB[1] + k2, pb2 + dB[1]);
            asm volatile("s_waitcnt vmcnt(6)" ::: "memory");   // tile t landed
        } else if (t == 30) {
            asm volatile("s_waitcnt vmcnt(3)" ::: "memory");
        } else {
            asm volatile("s_waitcnt vmcnt(0)" ::: "memory");
        }
        asm volatile("s_barrier" ::: "memory");                 // all waves' tile t in LDS

        bf16x8 a0, a1, a2, a3, b0, b1;
        a0 = ds_read128(pa0 + offA[0]);
        a1 = ds_read128(pa0 + offA[1]);
        a2 = ds_read128(pa0 + offA[2]);
        a3 = ds_read128(pa0 + offA[3]);
        b0 = ds_read128(pb0 + offB[0]);
        b1 = ds_read128(pb0 + offB[1]);
        asm volatile("s_waitcnt lgkmcnt(0)"
                     : "+v"(a0), "+v"(a1), "+v"(a2), "+v"(a3), "+v"(b0), "+v"(b1)
                     :: "memory");
        __builtin_amdgcn_s_setprio(1);
        acc[0][0] = MFMA16(a0, b0, acc[0][0]);
        acc[1][0] = MFMA16(a1, b0, acc[1][0]);
        acc[2][0] = MFMA16(a2, b0, acc[2][0]);
        acc[3][0] = MFMA16(a3, b0, acc[3][0]);
        acc[0][1] = MFMA16(a0, b1, acc[0][1]);
        acc[1][1] = MFMA16(a1, b1, acc[1][1]);
        acc[2][1] = MFMA16(a2, b1, acc[2][1]);
        acc[3][1] = MFMA16(a3, b1, acc[3][1]);
        __builtin_amdgcn_s_setprio(0);
        asm volatile("s_barrier" ::: "memory");                 // reads done -> stage reusable

        lds_us* tp = pa0; pa0 = pa1; pa1 = pa2; pa2 = tp;
        tp = pb0; pb0 = pb1; pb1 = pb2; pb2 = tp;
    }

    // epilogue. C/D layout: col = lane&15, row = quad*4 + r  (m89/m91 verified)
    const int gn_base = ntile * 128 + w * 32;
    if (PHASE == 0) {
#pragma unroll
        for (int mi = 0; mi < 4; mi++)
#pragma unroll
            for (int r = 0; r < 4; r++) {
                const int slot = mtile * 64 + mi * 16 + quad * 4 + r;
                unsigned short* outrow = hout + ((size_t)be * CK + slot) * CD;
#pragma unroll
                for (int ni = 0; ni < 2; ni++) {
                    const int col = gn_base + ni * 16 + lr;
                    float hv = acc[mi][ni][r] + bias[e * CD + col];
                    hv = fmaxf(hv, 0.0f);
                    outrow[col] = f2bf(hv);
                }
            }
    } else {
#pragma unroll
        for (int mi = 0; mi < 4; mi++)
#pragma unroll
            for (int r = 0; r < 4; r++) {
                const int slot = mtile * 64 + mi * 16 + quad * 4 + r;
                const int tok = idx_ws[be * CK + slot];
                const float gval = g_ws[be * CK + slot];
                float* yrow = y + ((size_t)b * CS + tok) * CD;
#pragma unroll
                for (int ni = 0; ni < 2; ni++) {
                    const int col = gn_base + ni * 16 + lr;
                    const float val = (acc[mi][ni][r] + bias[col]) * gval;
                    atomicAdd(&yrow[col], val);
                }
            }
    }
}

extern "C" void kernel_launch(void* const* d_in, const int* in_sizes, int n_in,
                              void* d_out, int out_size, void* d_ws, size_t ws_size,
                              hipStream_t stream) {
    const float* x    = (const float*)d_in[0];
    const float* gate = (const float*)d_in[1];
    const float* W1   = (const float*)d_in[2];
    const float* b1   = (const float*)d_in[3];
    const float* W2   = (const float*)d_in[4];
    const float* b2   = (const float*)d_in[5];
    float* y = (float*)d_out;

    // workspace layout (bytes):
    //   idx:    262144    .. +32768
    //   g:      294912    .. +32768
    //   xin:    327680    .. +16.78MB   (bf16)
    //   hbuf:   17104896  .. +16.78MB   (bf16)  [aliased: logits partials 4MB]
    //   Wt:     33882112  .. +33.55MB   (bf16, W1 then reused for W2)
    char* ws = (char*)d_ws;
    int* idxw = (int*)(ws + 262144);
    float* gw = (float*)(ws + 294912);
    unsigned short* xinbuf = (unsigned short*)(ws + 327680);
    unsigned short* hbuf = (unsigned short*)(ws + 17104896);
    float* partbuf = (float*)(ws + 17104896);   // lifetime disjoint from hbuf
    unsigned short* wtbuf = (unsigned short*)(ws + 33882112);

    // 6 launches (was 9): memset folded into K1a, reduce folded into topk,
    // gather+wt(W1) fused.
    logits_part_kernel<<<dim3(16, 16), 256, 0, stream>>>(x, gate, partbuf, y);
    topk_kernel<<<CB * CE, 256, 0, stream>>>(partbuf, idxw, gw);
    prep_kernel<<<4096 + CB * CE * CK, 256, 0, stream>>>(W1, wtbuf, x, idxw, xinbuf);
    ffn_gemm<0><<<1024, 256, 0, stream>>>(xinbuf, wtbuf, b1, hbuf, idxw, gw, y);
    wt_kernel<<<dim3(16, 16, CE), 256, 0, stream>>>(W2, wtbuf);
    ffn_gemm<1><<<1024, 256, 0, stream>>>(hbuf, wtbuf, b2, nullptr, idxw, gw, y);
}

// Round 3
// 271.835 us; speedup vs baseline: 1.0792x; 1.0792x over previous
//
#include <hip/hip_runtime.h>
#include <stdint.h>
#include <math.h>

// Problem constants (fixed by the reference)
constexpr int CB = 2;      // batch
constexpr int CS = 2048;   // seq (cutoff)
constexpr int CD = 1024;   // dmodel
constexpr int CE = 16;     // experts
constexpr int CK = 256;    // topk

typedef short bf16x8 __attribute__((ext_vector_type(8)));
typedef float f32x4 __attribute__((ext_vector_type(4)));

typedef __attribute__((address_space(1))) const unsigned int gu32;
typedef __attribute__((address_space(3))) unsigned int lu32;
typedef __attribute__((address_space(3))) unsigned short lds_us;

__device__ __forceinline__ void async16(const void* g, lds_us* l) {
    __builtin_amdgcn_global_load_lds((gu32*)g, (lu32*)l, 16, 0, 0);
}

// ds_read_b128 hidden from the waitcnt legalizer (it would otherwise insert
// s_waitcnt vmcnt(0) before any visible LDS read aliasing the LDS-DMA).
__device__ __forceinline__ bf16x8 ds_read128(const lds_us* p) {
    bf16x8 v;
    asm volatile("ds_read_b128 %0, %1" : "=v"(v) : "v"(p));
    return v;
}

__device__ inline unsigned short f2bf(float f) {
    union { float f; uint32_t u; } v; v.f = f;
    uint32_t u = v.u;
    uint32_t r = (u + 0x7FFFu + ((u >> 16) & 1u)) >> 16;
    return (unsigned short)r;
}

// ---------------- K1a: partial logits over a 64-d slice (+ zero y) ----------
__global__ __launch_bounds__(256)
void logits_part_kernel(const float* __restrict__ x,
                        const float* __restrict__ gate,
                        float* __restrict__ part,
                        float* __restrict__ y) {
    const int tt = blockIdx.x;       // token tile (256 tokens)
    const int dt = blockIdx.y;       // d tile (64 d)
    const int tid = threadIdx.x;

    // fold the y-zeroing in here (saves a hipMemsetAsync launch node).
    {
        const int bb = dt * 16 + tt;
        float* yb = y + (size_t)bb * 16384 + tid * 4;
        const f32x4 z = {0.f, 0.f, 0.f, 0.f};
#pragma unroll
        for (int i = 0; i < 16; i++) *(f32x4*)(yb + i * 1024) = z;
    }

    __shared__ float Xs[256 * 17];

    float acc[CE];
#pragma unroll
    for (int e = 0; e < CE; e++) acc[e] = 0.0f;

    const int tokl = tid >> 2;           // staging row within 64-token group
    const int c4 = (tid & 3) << 2;       // staging col (0,4,8,12)

    for (int dch = 0; dch < 4; dch++) {
        const int dbase = dt * 64 + dch * 16;
        __syncthreads();
#pragma unroll
        for (int q = 0; q < 4; q++) {
            const int tok = q * 64 + tokl;
            const f32x4 v = *(const f32x4*)(x + ((size_t)(tt * 256 + tok)) * CD + dbase + c4);
            Xs[tok * 17 + c4 + 0] = v[0];
            Xs[tok * 17 + c4 + 1] = v[1];
            Xs[tok * 17 + c4 + 2] = v[2];
            Xs[tok * 17 + c4 + 3] = v[3];
        }
        __syncthreads();
#pragma unroll
        for (int d = 0; d < 16; d++) {
            const float xv = Xs[tid * 17 + d];
            const float* gr = gate + (size_t)(dbase + d) * CE;  // wave-uniform
#pragma unroll
            for (int e = 0; e < CE; e++) acc[e] = fmaf(xv, gr[e], acc[e]);
        }
    }
    float* pr = part + ((size_t)dt * (CB * CS) + tt * 256 + tid) * CE;
#pragma unroll
    for (int e = 0; e < CE; e++) pr[e] = acc[e];
}

// ---------------- K1b: deterministic reduce of the 16 d-partials -------------
// (restored as its own launch: folding it into the 32-block topk serialized a
//  16 MB read onto 12.5% of the CUs and cost ~10 us e2e in R2)
__global__ __launch_bounds__(256)
void logits_reduce_kernel(const float* __restrict__ part,
                          float* __restrict__ logits) {
    const int i = blockIdx.x * 256 + threadIdx.x;   // 0 .. B*S*E-1
    float s = 0.0f;
#pragma unroll
    for (int p = 0; p < 16; p++) s += part[(size_t)p * (CB * CS * CE) + i];
    logits[i] = s;
}

// ---------------- K2: per (b,e) softmax over tokens + top-256 ----------------
__global__ void topk_kernel(const float* __restrict__ logits,
                            int* __restrict__ idx_out,
                            float* __restrict__ g_out) {
    const int be = blockIdx.x;            // b*E + e
    const int b = be >> 4, e = be & 15;
    const int tid = threadIdx.x;          // 256
    const int lane = tid & 63, wid = tid >> 6;

    __shared__ float redf[4];
    __shared__ int hist[256];
    __shared__ int wsum[4];
    __shared__ int sh_bin, sh_rank;
    __shared__ int scnt, eqc;
    __shared__ int eqbuf[CS];

    float lv[8], p[8];
    unsigned int uv[8];
#pragma unroll
    for (int j = 0; j < 8; j++) {
        const int s = tid + j * 256;
        lv[j] = logits[((size_t)(b * CS + s)) * CE + e];
    }
    float m = lv[0];
#pragma unroll
    for (int j = 1; j < 8; j++) m = fmaxf(m, lv[j]);
#pragma unroll
    for (int o = 32; o > 0; o >>= 1) m = fmaxf(m, __shfl_down(m, o));
    if (lane == 0) redf[wid] = m;
    __syncthreads();
    m = fmaxf(fmaxf(redf[0], redf[1]), fmaxf(redf[2], redf[3]));
    __syncthreads();
    float lsum = 0.0f;
#pragma unroll
    for (int j = 0; j < 8; j++) {
        p[j] = expf(lv[j] - m);
        uv[j] = __float_as_uint(p[j]);
        lsum += p[j];
    }
#pragma unroll
    for (int o = 32; o > 0; o >>= 1) lsum += __shfl_down(lsum, o);
    if (lane == 0) redf[wid] = lsum;
    __syncthreads();
    const float total = redf[0] + redf[1] + redf[2] + redf[3];
    const float inv_total = 1.0f / total;

    // ---- radix-256 select: find v = CK-th largest bit pattern ----
    unsigned int prefix = 0;
    int kneed = CK;
    for (int pass = 0; pass < 4; pass++) {
        const int shift = 24 - 8 * pass;
        __syncthreads();
        hist[tid] = 0;
        __syncthreads();
        const unsigned int hmask = (pass == 0) ? 0u : (0xFFFFFFFFu << (shift + 8));
#pragma unroll
        for (int j = 0; j < 8; j++)
            if ((uv[j] & hmask) == prefix)
                atomicAdd(&hist[(uv[j] >> shift) & 255], 1);
        __syncthreads();
        const int own = hist[tid];
        int s = own;
#pragma unroll
        for (int o = 1; o < 64; o <<= 1) {
            int t = __shfl_down(s, o);
            if (lane + o < 64) s += t;
        }
        if (lane == 0) wsum[wid] = s;
        __syncthreads();
        int above = 0;
        for (int ww = wid + 1; ww < 4; ww++) above += wsum[ww];
        const int incl = s + above;
        if (incl >= kneed && (incl - own) < kneed) {
            sh_bin = tid;
            sh_rank = kneed - (incl - own);
        }
        __syncthreads();
        prefix |= ((unsigned int)sh_bin) << shift;
        kneed = sh_rank;
    }
    const unsigned int v = prefix;
    const int quota = kneed;

    if (tid == 0) { scnt = 0; eqc = 0; }
    __syncthreads();
#pragma unroll
    for (int j = 0; j < 8; j++) {
        const int s = tid + j * 256;
        if (uv[j] > v) {
            const int pos = atomicAdd(&scnt, 1);
            idx_out[be * CK + pos] = s;
            g_out[be * CK + pos] = p[j] * inv_total;
        } else if (uv[j] == v) {
            const int pos = atomicAdd(&eqc, 1);
            eqbuf[pos] = s;
        }
    }
    __syncthreads();
    if (tid == 0) {
        const int cgt = scnt;
        const int n = eqc;
        const float gv = __uint_as_float(v) * inv_total;
        if (n > quota) {
            for (int i = 0; i < quota; i++) {
                int mn = i;
                for (int k2 = i + 1; k2 < n; k2++)
                    if (eqbuf[k2] < eqbuf[mn]) mn = k2;
                const int t2 = eqbuf[i]; eqbuf[i] = eqbuf[mn]; eqbuf[mn] = t2;
            }
        }
        for (int i = 0; i < quota; i++) {
            idx_out[be * CK + cgt + i] = eqbuf[i];
            g_out[be * CK + cgt + i] = gv;
        }
    }
}

// ---------------- wt transpose body: W[e][k][n] fp32 -> Wt[e][n][k] bf16 -----
__device__ __forceinline__
void wt_body(const float* __restrict__ W, unsigned short* __restrict__ Wt,
             int kt, int nt, int e, int tid, unsigned short* T) {
    const float* src = W + (size_t)e * CD * CD;
    unsigned short* dst = Wt + (size_t)e * CD * CD;

    const int kr = tid >> 4;            // 0..15
    const int n4 = (tid & 15) << 2;     // 0,4,..,60
#pragma unroll
    for (int it = 0; it < 4; it++) {
        const int k = it * 16 + kr;                    // tile-local k 0..63
        const f32x4 v = *(const f32x4*)(src + (size_t)(kt * 64 + k) * CD + nt * 64 + n4);
        const int pp = k >> 4;                          // 16-short chunk 0..3
        const int klo = k & 15;
#pragma unroll
        for (int i = 0; i < 4; i++) {
            const int n = n4 + i;
            T[n * 64 + ((pp ^ ((n >> 2) & 3)) << 4) + klo] = f2bf(v[i]);
        }
    }
    __syncthreads();
    const int n = tid >> 2;             // 0..63
    const int pp = tid & 3;             // output k-chunk
    const int sw = pp ^ ((n >> 2) & 3);
    const uint4 a = *(const uint4*)&T[n * 64 + (sw << 4)];
    const uint4 b = *(const uint4*)&T[n * 64 + (sw << 4) + 8];
    unsigned short* drow = dst + (size_t)(nt * 64 + n) * CD + kt * 64 + pp * 16;
    *(uint4*)drow = a;
    *(uint4*)(drow + 8) = b;
}

__global__ __launch_bounds__(256)
void wt_kernel(const float* __restrict__ W, unsigned short* __restrict__ Wt) {
    __shared__ unsigned short T[64 * 64];
    wt_body(W, Wt, blockIdx.x, blockIdx.y, blockIdx.z, threadIdx.x, T);
}

// ---------------- prep: wt(W1) and gather fused (one launch) -----------------
__global__ __launch_bounds__(256)
void prep_kernel(const float* __restrict__ W1, unsigned short* __restrict__ Wt,
                 const float* __restrict__ x, const int* __restrict__ idx_ws,
                 unsigned short* __restrict__ xinbuf) {
    __shared__ unsigned short T[64 * 64];
    const int bx = blockIdx.x;
    if (bx < 4096) {
        // wt(W1): kt = bx&15, nt = (bx>>4)&15, e = bx>>8
        wt_body(W1, Wt, bx & 15, (bx >> 4) & 15, bx >> 8, threadIdx.x, T);
    } else {
        // gather selected tokens -> bf16
        const int row = bx - 4096;             // be*CK + slot
        const int be = row >> 8;
        const int b = be >> 4;
        const int tok = idx_ws[row];
        const int c0 = threadIdx.x * 4;
        const f32x4 f = *(const f32x4*)(x + ((size_t)b * CS + tok) * CD + c0);
        union { unsigned short u[4]; uint2 v; } t;
        t.u[0] = f2bf(f[0]); t.u[1] = f2bf(f[1]); t.u[2] = f2bf(f[2]); t.u[3] = f2bf(f[3]);
        *(uint2*)(xinbuf + (size_t)row * CD + c0) = t.v;
    }
}

// ---------------- K5/K6: batched GEMM per (b,e), 2 FAT phases per K-tile -----
// R1 geometry unchanged (proven correct): tile 256x128, BK=64, 512 threads =
// 8 waves 4(M)x2(N), 64x64/wave, 3-deep LDS ring 144 KB, grid 256 (1/CU),
// XOR swizzle (u&7)^(row&7) on global source + swizzled ds_read offsets.
// CHANGED: loop regrouped from 4 thin phases (8 MFMA) to 2 fat phases per
// K-tile, one per kk: {8x ds_read_b128 + 3 gloads -> barrier -> lgkmcnt(0) ->
// setprio(1) + 16 MFMA + setprio(0) -> barrier}. Phases/block 64 -> 32.
// Theory: R0/R1/R2 showed per-CU barrier'd-phase throughput is the invariant
// (~750 ns/phase regardless of schedule or blocks/CU); halving phase count at
// constant per-phase cost should halve GEMM time.
#define MFMA16(A_, B_, C_) __builtin_amdgcn_mfma_f32_16x16x32_bf16((A_), (B_), (C_), 0, 0, 0)

template <int PHASE>
__global__ __launch_bounds__(512, 1)
void ffn_gemm(const unsigned short* __restrict__ Ain,
              const unsigned short* __restrict__ Wt,
              const float* __restrict__ bias,
              unsigned short* __restrict__ hout,
              const int* __restrict__ idx_ws,
              const float* __restrict__ g_ws,
              float* __restrict__ y) {
    const int id = blockIdx.x;            // 0..255
    const int xcd = id & 7;
    const int q = id >> 3;                // 0..31
    const int e = ((q & 1) << 3) | xcd;
    const int b = (q >> 1) & 1;
    const int ntile = q >> 2;             // 0..7
    const int be = b * CE + e;
    const int tid = threadIdx.x;
    const int w = tid >> 6, l = tid & 63;
    const int wm = w >> 1, wn = w & 1;    // wave grid 4(M) x 2(N)
    const int quad = l >> 4, lr = l & 15;

    __shared__ __align__(16) unsigned short LA[3][256 * 64];   // 3 x 32 KB
    __shared__ __align__(16) unsigned short LB[3][128 * 64];   // 3 x 16 KB

    f32x4 acc[4][4];
    const f32x4 zz = {0.f, 0.f, 0.f, 0.f};
#pragma unroll
    for (int mi = 0; mi < 4; mi++)
#pragma unroll
        for (int ni = 0; ni < 4; ni++) acc[mi][ni] = zz;

    const unsigned short* Agb = Ain + (size_t)be * CK * CD;                 // [256][1024]
    const unsigned short* Bgb = Wt + ((size_t)e * CD + ntile * 128) * CD;   // [128][1024]

    // staging geometry (t-independent): unit u = one 16B chunk of the LDS tile.
    // LDS is lane-linear (DMA constraint); global chunk c = (u&7) ^ (row&7).
    const unsigned short* pAg[4]; int dA[4];
#pragma unroll
    for (int j = 0; j < 4; j++) {
        const int u = w * 256 + j * 64 + l;      // 0..2047
        const int row = u >> 3;
        const int c = (u & 7) ^ (row & 7);
        pAg[j] = Agb + (size_t)row * CD + c * 8;
        dA[j] = u * 8;
    }
    const unsigned short* pBg[2]; int dB[2];
#pragma unroll
    for (int j = 0; j < 2; j++) {
        const int u = w * 128 + j * 64 + l;      // 0..1023
        const int row = u >> 3;
        const int c = (u & 7) ^ (row & 7);
        pBg[j] = Bgb + (size_t)row * CD + c * 8;
        dB[j] = u * 8;
    }

    // fragment read offsets (ushort units): row*64 + ((kk*4+quad)^(row&7))*8
    const int sc0 = (quad ^ (lr & 7)) * 8;
    const int sc1 = ((quad ^ (lr & 7)) ^ 4) * 8;   // 4+quad == 4^quad for quad<4
    int offA[2][4], offB[2][4];
#pragma unroll
    for (int mi = 0; mi < 4; mi++) {
        const int r = wm * 64 + mi * 16 + lr;
        offA[0][mi] = r * 64 + sc0;
        offA[1][mi] = r * 64 + sc1;
    }
#pragma unroll
    for (int ni = 0; ni < 4; ni++) {
        const int r = wn * 64 + ni * 16 + lr;
        offB[0][ni] = r * 64 + sc0;
        offB[1][ni] = r * 64 + sc1;
    }

    lds_us* pA0 = (lds_us*)LA[0]; lds_us* pA1 = (lds_us*)LA[1]; lds_us* pA2 = (lds_us*)LA[2];
    lds_us* pB0 = (lds_us*)LB[0]; lds_us* pB1 = (lds_us*)LB[1]; lds_us* pB2 = (lds_us*)LB[2];

    // prologue: tiles 0 and 1 (6 load-instr per wave each)
#pragma unroll
    for (int j = 0; j < 4; j++) async16(pAg[j], pA0 + dA[j]);
#pragma unroll
    for (int j = 0; j < 2; j++) async16(pBg[j], pB0 + dB[j]);
#pragma unroll
    for (int j = 0; j < 4; j++) async16(pAg[j] + 64, pA1 + dA[j]);
#pragma unroll
    for (int j = 0; j < 2; j++) async16(pBg[j] + 64, pB1 + dB[j]);
    asm volatile("s_waitcnt vmcnt(6)" ::: "memory");   // tile 0 landed
    asm volatile("s_barrier" ::: "memory");

    for (int t = 0; t < 16; t++) {
        const bool pf = (t + 2) < 16;
        const int kel = (t + 2) * 64;
        bf16x8 a0, a1, a2, a3, b0, b1, b2, b3;

        // ---- phase 0: kk=0, all 16 MFMA ----
        a0 = ds_read128(pA0 + offA[0][0]);
        a1 = ds_read128(pA0 + offA[0][1]);
        a2 = ds_read128(pA0 + offA[0][2]);
        a3 = ds_read128(pA0 + offA[0][3]);
        b0 = ds_read128(pB0 + offB[0][0]);
        b1 = ds_read128(pB0 + offB[0][1]);
        b2 = ds_read128(pB0 + offB[0][2]);
        b3 = ds_read128(pB0 + offB[0][3]);
        if (pf) {
            async16(pAg[0] + kel, pA2 + dA[0]);
            async16(pAg[1] + kel, pA2 + dA[1]);
            async16(pAg[2] + kel, pA2 + dA[2]);
        }
        asm volatile("s_barrier" ::: "memory");
        asm volatile("s_waitcnt lgkmcnt(0)"
                     : "+v"(a0), "+v"(a1), "+v"(a2), "+v"(a3),
                       "+v"(b0), "+v"(b1), "+v"(b2), "+v"(b3) :: "memory");
        __builtin_amdgcn_s_setprio(1);
        acc[0][0] = MFMA16(a0, b0, acc[0][0]);
        acc[1][0] = MFMA16(a1, b0, acc[1][0]);
        acc[2][0] = MFMA16(a2, b0, acc[2][0]);
        acc[3][0] = MFMA16(a3, b0, acc[3][0]);
        acc[0][1] = MFMA16(a0, b1, acc[0][1]);
        acc[1][1] = MFMA16(a1, b1, acc[1][1]);
        acc[2][1] = MFMA16(a2, b1, acc[2][1]);
        acc[3][1] = MFMA16(a3, b1, acc[3][1]);
        acc[0][2] = MFMA16(a0, b2, acc[0][2]);
        acc[1][2] = MFMA16(a1, b2, acc[1][2]);
        acc[2][2] = MFMA16(a2, b2, acc[2][2]);
        acc[3][2] = MFMA16(a3, b2, acc[3][2]);
        acc[0][3] = MFMA16(a0, b3, acc[0][3]);
        acc[1][3] = MFMA16(a1, b3, acc[1][3]);
        acc[2][3] = MFMA16(a2, b3, acc[2][3]);
        acc[3][3] = MFMA16(a3, b3, acc[3][3]);
        __builtin_amdgcn_s_setprio(0);
        asm volatile("s_barrier" ::: "memory");

        // ---- phase 1: kk=1, all 16 MFMA ----
        a0 = ds_read128(pA0 + offA[1][0]);
        a1 = ds_read128(pA0 + offA[1][1]);
        a2 = ds_read128(pA0 + offA[1][2]);
        a3 = ds_read128(pA0 + offA[1][3]);
        b0 = ds_read128(pB0 + offB[1][0]);
        b1 = ds_read128(pB0 + offB[1][1]);
        b2 = ds_read128(pB0 + offB[1][2]);
        b3 = ds_read128(pB0 + offB[1][3]);
        if (pf) {
            async16(pAg[3] + kel, pA2 + dA[3]);
            async16(pBg[0] + kel, pB2 + dB[0]);
            async16(pBg[1] + kel, pB2 + dB[1]);
        }
        asm volatile("s_barrier" ::: "memory");
        asm volatile("s_waitcnt lgkmcnt(0)"
                     : "+v"(a0), "+v"(a1), "+v"(a2), "+v"(a3),
                       "+v"(b0), "+v"(b1), "+v"(b2), "+v"(b3) :: "memory");
        __builtin_amdgcn_s_setprio(1);
        acc[0][0] = MFMA16(a0, b0, acc[0][0]);
        acc[1][0] = MFMA16(a1, b0, acc[1][0]);
        acc[2][0] = MFMA16(a2, b0, acc[2][0]);
        acc[3][0] = MFMA16(a3, b0, acc[3][0]);
        acc[0][1] = MFMA16(a0, b1, acc[0][1]);
        acc[1][1] = MFMA16(a1, b1, acc[1][1]);
        acc[2][1] = MFMA16(a2, b1, acc[2][1]);
        acc[3][1] = MFMA16(a3, b1, acc[3][1]);
        acc[0][2] = MFMA16(a0, b2, acc[0][2]);
        acc[1][2] = MFMA16(a1, b2, acc[1][2]);
        acc[2][2] = MFMA16(a2, b2, acc[2][2]);
        acc[3][2] = MFMA16(a3, b2, acc[3][2]);
        acc[0][3] = MFMA16(a0, b3, acc[0][3]);
        acc[1][3] = MFMA16(a1, b3, acc[1][3]);
        acc[2][3] = MFMA16(a2, b3, acc[2][3]);
        acc[3][3] = MFMA16(a3, b3, acc[3][3]);
        __builtin_amdgcn_s_setprio(0);
        // tile t+1 must be fully landed before we rotate into it:
        // outstanding here = t+2's 6 (just issued) + t+1's <=6 -> vmcnt(6).
        if (t < 14)       asm volatile("s_waitcnt vmcnt(6)" ::: "memory");
        else if (t == 14) asm volatile("s_waitcnt vmcnt(0)" ::: "memory");
        asm volatile("s_barrier" ::: "memory");

        lds_us* tp = pA0; pA0 = pA1; pA1 = pA2; pA2 = tp;
        tp = pB0; pB0 = pB1; pB1 = pB2; pB2 = tp;
    }

    // epilogue. C/D layout: col = lane&15, row = quad*4 + r  (m89/m91 verified)
    const int gn_base = ntile * 128 + wn * 64;
    if (PHASE == 0) {
#pragma unroll
        for (int mi = 0; mi < 4; mi++)
#pragma unroll
            for (int r = 0; r < 4; r++) {
                const int slot = wm * 64 + mi * 16 + quad * 4 + r;
                unsigned short* outrow = hout + ((size_t)be * CK + slot) * CD;
#pragma unroll
                for (int ni = 0; ni < 4; ni++) {
                    const int col = gn_base + ni * 16 + lr;
                    float hv = acc[mi][ni][r] + bias[e * CD + col];
                    hv = fmaxf(hv, 0.0f);
                    outrow[col] = f2bf(hv);
                }
            }
    } else {
#pragma unroll
        for (int mi = 0; mi < 4; mi++)
#pragma unroll
            for (int r = 0; r < 4; r++) {
                const int slot = wm * 64 + mi * 16 + quad * 4 + r;
                const int tok = idx_ws[be * CK + slot];
                const float gval = g_ws[be * CK + slot];
                float* yrow = y + ((size_t)b * CS + tok) * CD;
#pragma unroll
                for (int ni = 0; ni < 4; ni++) {
                    const int col = gn_base + ni * 16 + lr;
                    const float val = (acc[mi][ni][r] + bias[col]) * gval;
                    atomicAdd(&yrow[col], val);
                }
            }
    }
}

extern "C" void kernel_launch(void* const* d_in, const int* in_sizes, int n_in,
                              void* d_out, int out_size, void* d_ws, size_t ws_size,
                              hipStream_t stream) {
    const float* x    = (const float*)d_in[0];
    const float* gate = (const float*)d_in[1];
    const float* W1   = (const float*)d_in[2];
    const float* b1   = (const float*)d_in[3];
    const float* W2   = (const float*)d_in[4];
    const float* b2   = (const float*)d_in[5];
    float* y = (float*)d_out;

    // workspace layout (bytes):
    //   logits: 0         .. 262144     (B*S*E fp32)
    //   idx:    262144    .. +32768
    //   g:      294912    .. +32768
    //   xin:    327680    .. +16.78MB   (bf16)
    //   hbuf:   17104896  .. +16.78MB   (bf16)  [aliased: logits partials 4MB]
    //   Wt:     33882112  .. +33.55MB   (bf16, W1 then reused for W2)
    char* ws = (char*)d_ws;
    float* logits = (float*)ws;
    int* idxw = (int*)(ws + 262144);
    float* gw = (float*)(ws + 294912);
    unsigned short* xinbuf = (unsigned short*)(ws + 327680);
    unsigned short* hbuf = (unsigned short*)(ws + 17104896);
    float* partbuf = (float*)(ws + 17104896);   // lifetime disjoint from hbuf
    unsigned short* wtbuf = (unsigned short*)(ws + 33882112);

    // 7 launches: memset folded into K1a, gather+wt(W1) fused; reduce restored.
    logits_part_kernel<<<dim3(16, 16), 256, 0, stream>>>(x, gate, partbuf, y);
    logits_reduce_kernel<<<CB * CS * CE / 256, 256, 0, stream>>>(partbuf, logits);
    topk_kernel<<<CB * CE, 256, 0, stream>>>(logits, idxw, gw);
    prep_kernel<<<4096 + CB * CE * CK, 256, 0, stream>>>(W1, wtbuf, x, idxw, xinbuf);
    ffn_gemm<0><<<256, 512, 0, stream>>>(xinbuf, wtbuf, b1, hbuf, idxw, gw, y);
    wt_kernel<<<dim3(16, 16, CE), 256, 0, stream>>>(W2, wtbuf);
    ffn_gemm<1><<<256, 512, 0, stream>>>(hbuf, wtbuf, b2, nullptr, idxw, gw, y);
}